// Round 1
// baseline (30710.699 us; speedup 1.0000x reference)
//
#include <hip/hip_runtime.h>
#include <stdint.h>

#define BB 4
#define SS 2048
#define HH 1024
#define NHH 16
#define HDD 64
#define M_TOT (BB*SS)          // 8192

// workspace layout (ushort/bf16 element offsets)
#define XB_OFF 0                              // hidden bf16 [8192][1024]
#define W_OFF  (M_TOT*HH)                     // Wq,Wk,Wv bf16 contiguous [3][1024][1024]
#define Q_OFF  (W_OFF + 3*HH*HH)              // Q  [B][NH][S][HD]
#define KT_OFF (Q_OFF + BB*NHH*SS*HDD)        // Kt [B][NH][HD][S]   (transposed!)
#define V_OFF  (KT_OFF + BB*NHH*SS*HDD)       // V  [B][NH][S][HD]

typedef short bf16x8 __attribute__((ext_vector_type(8)));
typedef float f32x4  __attribute__((ext_vector_type(4)));

__device__ inline unsigned short f2bf(float f){
  unsigned u = __float_as_uint(f);
  u += 0x7fffu + ((u >> 16) & 1u);   // RNE
  return (unsigned short)(u >> 16);
}
__device__ inline float bf2f(unsigned short h){
  return __uint_as_float(((unsigned)h) << 16);
}

// ---------------- kernel 1: fp32 -> bf16 conversion of X and W ----------------
__global__ void convert_kernel(const float* __restrict__ hs,
                               const float* __restrict__ wq,
                               const float* __restrict__ wk,
                               const float* __restrict__ wv,
                               unsigned short* __restrict__ ws16){
  const int n = M_TOT*HH + 3*HH*HH;
  for (int i = blockIdx.x*blockDim.x + threadIdx.x; i < n; i += gridDim.x*blockDim.x){
    float v;
    if (i < M_TOT*HH) v = hs[i];
    else {
      int j = i - M_TOT*HH;
      v = (j < HH*HH) ? wq[j] : (j < 2*HH*HH ? wk[j - HH*HH] : wv[j - 2*HH*HH]);
    }
    ws16[i] = f2bf(v);
  }
}

// ---------------- kernel 2: QKV projection GEMM (bf16 MFMA) ----------------
// grid (M/64, N/64, 3); block 256 (4 waves). wave -> 64x16 output tile (4 MFMAs/k-step).
__global__ __launch_bounds__(256) void qkv_gemm(
    const unsigned short* __restrict__ ws16, unsigned short* __restrict__ wsq,
    const float* __restrict__ bq, const float* __restrict__ bk, const float* __restrict__ bv,
    const float* __restrict__ qe, const float* __restrict__ ke, const float* __restrict__ ve,
    const int* __restrict__ idxp){
  const unsigned short* Xb = ws16 + XB_OFF;
  const int z = blockIdx.z;
  const unsigned short* Wb = ws16 + W_OFF + z*HH*HH;
  const float* bias = (z==0) ? bq : ((z==1) ? bk : bv);
  const float* emb  = (z==0) ? qe : ((z==1) ? ke : ve);
  const int index = idxp[0];

  const int tid  = threadIdx.x;
  const int wave = tid >> 6;
  const int lane = tid & 63;
  const int quad = lane >> 4;
  const int l15  = lane & 15;
  const int m0 = blockIdx.x * 64;
  const int n0 = blockIdx.y * 64 + wave * 16;

  f32x4 acc[4] = { {0,0,0,0}, {0,0,0,0}, {0,0,0,0}, {0,0,0,0} };

  for (int k0 = 0; k0 < HH; k0 += 32){
    const int kb = k0 + quad*8;
    bf16x8 bfr;
    #pragma unroll
    for (int j = 0; j < 8; j++)
      bfr[j] = (short)Wb[(kb + j)*HH + n0 + l15];    // B[k][n], n=lane&15, k=quad*8+j
    #pragma unroll
    for (int ms = 0; ms < 4; ms++){
      const int row = m0 + ms*16 + l15;              // A[m][k], m=lane&15
      bf16x8 afr = *(const bf16x8*)(Xb + row*HH + kb);
      acc[ms] = __builtin_amdgcn_mfma_f32_16x16x32_bf16(afr, bfr, acc[ms], 0, 0, 0);
    }
  }

  const int n  = n0 + l15;
  const float biasv = bias[n] + emb[index*HH + n];
  const int h = n >> 6, d = n & 63;
  #pragma unroll
  for (int ms = 0; ms < 4; ms++){
    #pragma unroll
    for (int r = 0; r < 4; r++){
      const int g  = m0 + ms*16 + quad*4 + r;        // C/D: row=quad*4+reg, col=lane&15
      const int b_ = g >> 11;                        // /2048
      const int s_ = g & (SS - 1);
      const unsigned short val = f2bf(acc[ms][r] + biasv);
      const int bh = b_*NHH + h;
      if (z == 1)      wsq[KT_OFF + (bh*HDD + d)*SS + s_] = val;   // K transposed
      else if (z == 0) wsq[Q_OFF  + (bh*SS + s_)*HDD + d] = val;
      else             wsq[V_OFF  + (bh*SS + s_)*HDD + d] = val;
    }
  }
}

// ---------------- kernel 3: flash attention (online softmax, fp32 math) ----------------
// block 256 = 4 waves; each wave handles 2 query rows. grid = B*NH*S/8.
__global__ __launch_bounds__(256) void attn_kernel(
    const unsigned short* __restrict__ ws16,
    const float* __restrict__ mask, float* __restrict__ out){
  __shared__ float qs[4][64][2];
  __shared__ float ps[4][64][2];

  const int tid  = threadIdx.x;
  const int wave = tid >> 6;
  const int lane = tid & 63;
  const int bid  = blockIdx.x;
  const int rb   = bid & 255;            // 256 row-blocks of 8 per (b,h)
  const int bh   = bid >> 8;             // [0,64)
  const int b    = bh >> 4;
  const int h    = bh & 15;
  const int r0   = rb*8 + wave*2;

  const unsigned short* qb = ws16 + Q_OFF  + bh*SS*HDD;
  const unsigned short* kt = ws16 + KT_OFF + bh*HDD*SS;
  const unsigned short* vb = ws16 + V_OFF  + bh*SS*HDD;
  const float* mp = mask + b*SS;

  // stage this wave's two q rows into LDS (lane <-> d)
  qs[wave][lane][0] = bf2f(qb[(r0    )*HDD + lane]);
  qs[wave][lane][1] = bf2f(qb[(r0 + 1)*HDD + lane]);
  // same-wave DS ops are in-order; no barrier needed for intra-wave LDS use

  float m0 = -1e30f, m1 = -1e30f;
  float l0 = 0.f, l1 = 0.f;
  float o0 = 0.f, o1 = 0.f;

  for (int t = 0; t < 32; t++){
    // ---- scores for k = t*64 + lane (both rows) ----
    float s0 = 0.f, s1 = 0.f;
    const unsigned short* kp = kt + t*64 + lane;     // + d*S, lane-contiguous
    #pragma unroll
    for (int d = 0; d < 64; d++){
      const float kv = bf2f(kp[d*SS]);
      const float2 qq = *(const float2*)&qs[wave][d][0];
      s0 = fmaf(qq.x, kv, s0);
      s1 = fmaf(qq.y, kv, s1);
    }
    const float mk = mp[t*64 + lane];
    s0 = s0*0.125f + mk;                              // 1/sqrt(64)
    s1 = s1*0.125f + mk;

    // ---- online softmax update ----
    float c0 = s0, c1 = s1;
    #pragma unroll
    for (int sh = 32; sh >= 1; sh >>= 1){
      c0 = fmaxf(c0, __shfl_xor(c0, sh));
      c1 = fmaxf(c1, __shfl_xor(c1, sh));
    }
    const float mn0 = fmaxf(m0, c0), mn1 = fmaxf(m1, c1);
    const float a0 = expf(m0 - mn0), a1 = expf(m1 - mn1);
    const float p0 = expf(s0 - mn0), p1 = expf(s1 - mn1);
    float su0 = p0, su1 = p1;
    #pragma unroll
    for (int sh = 32; sh >= 1; sh >>= 1){
      su0 += __shfl_xor(su0, sh);
      su1 += __shfl_xor(su1, sh);
    }
    l0 = l0*a0 + su0;
    l1 = l1*a1 + su1;
    m0 = mn0; m1 = mn1;

    // ---- broadcast p through LDS, accumulate o (lane <-> d) ----
    float2 pw; pw.x = p0; pw.y = p1;
    *(float2*)&ps[wave][lane][0] = pw;
    const unsigned short* vp = vb + t*64*HDD + lane;
    o0 *= a0; o1 *= a1;
    #pragma unroll
    for (int kk = 0; kk < 64; kk++){
      const float2 pp = *(const float2*)&ps[wave][kk][0];
      const float vv = bf2f(vp[kk*HDD]);
      o0 = fmaf(pp.x, vv, o0);
      o1 = fmaf(pp.y, vv, o1);
    }
  }

  out[(b*SS + r0    )*HH + h*HDD + lane] = o0 / l0;
  out[(b*SS + r0 + 1)*HH + h*HDD + lane] = o1 / l1;
}

extern "C" void kernel_launch(void* const* d_in, const int* in_sizes, int n_in,
                              void* d_out, int out_size, void* d_ws, size_t ws_size,
                              hipStream_t stream){
  const float* hs   = (const float*)d_in[0];
  const float* mask = (const float*)d_in[1];
  const float* Wq   = (const float*)d_in[2];
  const float* bq   = (const float*)d_in[3];
  const float* Wk   = (const float*)d_in[4];
  const float* bk   = (const float*)d_in[5];
  const float* Wv   = (const float*)d_in[6];
  const float* bv   = (const float*)d_in[7];
  const float* qe   = (const float*)d_in[8];
  const float* ke   = (const float*)d_in[9];
  const float* ve   = (const float*)d_in[10];
  const int*   idx  = (const int*)d_in[11];
  unsigned short* ws16 = (unsigned short*)d_ws;
  float* out = (float*)d_out;

  convert_kernel<<<4096, 256, 0, stream>>>(hs, Wq, Wk, Wv, ws16);

  dim3 g2(M_TOT/64, HH/64, 3);
  qkv_gemm<<<g2, 256, 0, stream>>>(ws16, ws16, bq, bk, bv, qe, ke, ve, idx);

  attn_kernel<<<BB*NHH*SS/8, 256, 0, stream>>>(ws16, mask, out);
}

// Round 2
// 830.200 us; speedup vs baseline: 36.9919x; 36.9919x over previous
//
#include <hip/hip_runtime.h>
#include <stdint.h>

#define BB 4
#define SS 2048
#define HH 1024
#define NHH 16
#define HDD 64
#define M_TOT (BB*SS)          // 8192

// workspace layout (ushort/bf16 element offsets)
#define XB_OFF 0                              // hidden bf16 [8192][1024]
#define W_OFF  (M_TOT*HH)                     // Wq,Wk,Wv bf16 contiguous [3][1024][1024]
#define Q_OFF  (W_OFF + 3*HH*HH)              // Q  [B][NH][S][HD]
#define K_OFF  (Q_OFF + BB*NHH*SS*HDD)        // K  [B][NH][S][HD]
#define VT_OFF (K_OFF + BB*NHH*SS*HDD)        // Vt [B][NH][HD][S]  (transposed)

typedef short bf16x8 __attribute__((ext_vector_type(8)));
typedef short bf16x4 __attribute__((ext_vector_type(4)));
typedef float f32x4  __attribute__((ext_vector_type(4)));

__device__ inline unsigned short f2bf(float f){
  unsigned u = __float_as_uint(f);
  u += 0x7fffu + ((u >> 16) & 1u);   // RNE
  return (unsigned short)(u >> 16);
}
__device__ inline float bf2f(unsigned short h){
  return __uint_as_float(((unsigned)h) << 16);
}

// ---------------- kernel 1: fp32 -> bf16 conversion of X and W ----------------
__global__ void convert_kernel(const float* __restrict__ hs,
                               const float* __restrict__ wq,
                               const float* __restrict__ wk,
                               const float* __restrict__ wv,
                               unsigned short* __restrict__ ws16){
  const int n = M_TOT*HH + 3*HH*HH;
  for (int i = blockIdx.x*blockDim.x + threadIdx.x; i < n; i += gridDim.x*blockDim.x){
    float v;
    if (i < M_TOT*HH) v = hs[i];
    else {
      int j = i - M_TOT*HH;
      v = (j < HH*HH) ? wq[j] : (j < 2*HH*HH ? wk[j - HH*HH] : wv[j - 2*HH*HH]);
    }
    ws16[i] = f2bf(v);
  }
}

// ---------------- kernel 2: QKV projection GEMM (bf16 MFMA) ----------------
// grid (M/64, N/64, 3); block 256 (4 waves). wave -> 64x16 output tile.
__global__ __launch_bounds__(256) void qkv_gemm(
    const unsigned short* __restrict__ ws16, unsigned short* __restrict__ wsq,
    const float* __restrict__ bq, const float* __restrict__ bk, const float* __restrict__ bv,
    const float* __restrict__ qe, const float* __restrict__ ke, const float* __restrict__ ve,
    const int* __restrict__ idxp){
  const unsigned short* Xb = ws16 + XB_OFF;
  const int z = blockIdx.z;
  const unsigned short* Wb = ws16 + W_OFF + z*HH*HH;
  const float* bias = (z==0) ? bq : ((z==1) ? bk : bv);
  const float* emb  = (z==0) ? qe : ((z==1) ? ke : ve);
  const int index = idxp[0];

  const int tid  = threadIdx.x;
  const int wave = tid >> 6;
  const int lane = tid & 63;
  const int quad = lane >> 4;
  const int l15  = lane & 15;
  const int m0 = blockIdx.x * 64;
  const int n0 = blockIdx.y * 64 + wave * 16;

  f32x4 acc[4] = { {0,0,0,0}, {0,0,0,0}, {0,0,0,0}, {0,0,0,0} };

  for (int k0 = 0; k0 < HH; k0 += 32){
    const int kb = k0 + quad*8;
    bf16x8 bfr;
    #pragma unroll
    for (int j = 0; j < 8; j++)
      bfr[j] = (short)Wb[(kb + j)*HH + n0 + l15];    // B[k][n]
    #pragma unroll
    for (int ms = 0; ms < 4; ms++){
      const int row = m0 + ms*16 + l15;              // A[m][k]
      bf16x8 afr = *(const bf16x8*)(Xb + row*HH + kb);
      acc[ms] = __builtin_amdgcn_mfma_f32_16x16x32_bf16(afr, bfr, acc[ms], 0, 0, 0);
    }
  }

  const int n  = n0 + l15;
  const float biasv = bias[n] + emb[index*HH + n];
  const int h = n >> 6, d = n & 63;
  #pragma unroll
  for (int ms = 0; ms < 4; ms++){
    #pragma unroll
    for (int r = 0; r < 4; r++){
      const int g  = m0 + ms*16 + quad*4 + r;        // C/D: row=quad*4+reg, col=lane&15
      const int b_ = g >> 11;
      const int s_ = g & (SS - 1);
      const unsigned short val = f2bf(acc[ms][r] + biasv);
      const int bh = b_*NHH + h;
      if (z == 2)      wsq[VT_OFF + (bh*HDD + d)*SS + s_] = val;   // V transposed
      else if (z == 0) wsq[Q_OFF  + (bh*SS + s_)*HDD + d] = val;
      else             wsq[K_OFF  + (bh*SS + s_)*HDD + d] = val;
    }
  }
}

// ---------------- kernel 3: MFMA flash attention ----------------
// block 256 = 4 waves, each wave owns 16 q rows (block tile = 64 q rows).
// kt-tile = 32. grid = (B*NH) * (S/64) = 2048 blocks.
#define ST_K 72   // klds row stride (bf16): 144B = 9 x 16B -> uniform bank groups
#define ST_P 36   // plds row stride (bf16): 72B -> 2-way max write conflicts
__global__ __launch_bounds__(256) void attn_mfma(
    const unsigned short* __restrict__ ws16,
    const float* __restrict__ mask, float* __restrict__ out){
  __shared__ unsigned short klds[32*ST_K];     // K tile [32 s][64 d] (padded)
  __shared__ unsigned short vlds[64*32];       // V tile [64 d][32 kt]
  __shared__ unsigned short plds[4][16*ST_P];  // per-wave P [16 m][32 kt] (padded)
  __shared__ float mlds[SS];                   // mask row for this b

  const int tid  = threadIdx.x;
  const int wave = tid >> 6;
  const int lane = tid & 63;
  const int quad = lane >> 4;
  const int l15  = lane & 15;
  const int qb   = blockIdx.x & 31;            // q-block within (b,h)
  const int bh   = blockIdx.x >> 5;
  const int b    = bh >> 4, h = bh & 15;
  const int q0   = qb*64 + wave*16;

  // stage mask row (2048 f32, 8 per thread)
  {
    const float4* mp = (const float4*)(mask + b*SS);
    float4 a = mp[tid*2 + 0], c = mp[tid*2 + 1];
    *(float4*)&mlds[tid*8 + 0] = a;
    *(float4*)&mlds[tid*8 + 4] = c;
  }

  const unsigned short* Qg = ws16 + Q_OFF  + (size_t)bh*SS*HDD;
  const unsigned short* Kg = ws16 + K_OFF  + (size_t)bh*SS*HDD;
  const unsigned short* Vg = ws16 + VT_OFF + (size_t)bh*HDD*SS;

  // Q A-frags, resident all kernel: A[m=l15][k=quad*8+j], k chunks {0,32}
  const bf16x8 aq0 = *(const bf16x8*)(Qg + (q0 + l15)*HDD + quad*8);
  const bf16x8 aq1 = *(const bf16x8*)(Qg + (q0 + l15)*HDD + 32 + quad*8);

  f32x4 O[4] = { {0,0,0,0}, {0,0,0,0}, {0,0,0,0}, {0,0,0,0} };
  float mr[4] = {-1e30f,-1e30f,-1e30f,-1e30f};
  float lr[4] = {0.f,0.f,0.f,0.f};

  const int krow = tid >> 3, kcol = (tid & 7)*8;
  const int vrow = tid >> 2, vcol = (tid & 3)*8;
  const float LOG2E = 1.4426950408889634f;

  for (int t = 0; t < 64; t++){
    __syncthreads();
    // stage K tile [32][64] and V tile [64][32] (both 16B/lane, coalesced)
    *(bf16x8*)&klds[krow*ST_K + kcol] = *(const bf16x8*)&Kg[(t*32 + krow)*HDD + kcol];
    *(bf16x8*)&vlds[vrow*32  + vcol] = *(const bf16x8*)&Vg[vrow*SS + t*32 + vcol];
    __syncthreads();

    // ---- QK^T: scores 16 x 32 in two C-frags ----
    f32x4 sc0 = {0,0,0,0}, sc1 = {0,0,0,0};
    {
      bf16x8 b00 = *(const bf16x8*)&klds[(l15     )*ST_K      + quad*8];
      bf16x8 b01 = *(const bf16x8*)&klds[(l15     )*ST_K + 32 + quad*8];
      bf16x8 b10 = *(const bf16x8*)&klds[(16 + l15)*ST_K      + quad*8];
      bf16x8 b11 = *(const bf16x8*)&klds[(16 + l15)*ST_K + 32 + quad*8];
      sc0 = __builtin_amdgcn_mfma_f32_16x16x32_bf16(aq0, b00, sc0, 0,0,0);
      sc0 = __builtin_amdgcn_mfma_f32_16x16x32_bf16(aq1, b01, sc0, 0,0,0);
      sc1 = __builtin_amdgcn_mfma_f32_16x16x32_bf16(aq0, b10, sc1, 0,0,0);
      sc1 = __builtin_amdgcn_mfma_f32_16x16x32_bf16(aq1, b11, sc1, 0,0,0);
    }

    // ---- scale + mask (col = t*32 + f*16 + l15) ----
    const float msk0 = mlds[t*32 + l15];
    const float msk1 = mlds[t*32 + 16 + l15];
    #pragma unroll
    for (int r = 0; r < 4; r++){
      sc0[r] = sc0[r]*0.125f + msk0;
      sc1[r] = sc1[r]*0.125f + msk1;
    }

    // ---- online softmax (rows = quad*4+r, cols across 16-lane group) ----
    float mx[4];
    #pragma unroll
    for (int r = 0; r < 4; r++) mx[r] = fmaxf(sc0[r], sc1[r]);
    #pragma unroll
    for (int sh = 1; sh < 16; sh <<= 1){
      #pragma unroll
      for (int r = 0; r < 4; r++) mx[r] = fmaxf(mx[r], __shfl_xor(mx[r], sh));
    }
    float al[4], su[4];
    #pragma unroll
    for (int r = 0; r < 4; r++){
      const float nm = fmaxf(mr[r], mx[r]);
      al[r] = exp2f((mr[r] - nm)*LOG2E);
      mr[r] = nm;
      sc0[r] = exp2f((sc0[r] - nm)*LOG2E);
      sc1[r] = exp2f((sc1[r] - nm)*LOG2E);
      su[r] = sc0[r] + sc1[r];
    }
    #pragma unroll
    for (int sh = 1; sh < 16; sh <<= 1){
      #pragma unroll
      for (int r = 0; r < 4; r++) su[r] += __shfl_xor(su[r], sh);
    }
    #pragma unroll
    for (int r = 0; r < 4; r++) lr[r] = lr[r]*al[r] + su[r];

    // ---- P (bf16) C-layout -> LDS (per-wave, no barrier needed) ----
    unsigned short* pw = &plds[wave][0];
    #pragma unroll
    for (int r = 0; r < 4; r++){
      pw[(quad*4 + r)*ST_P      + l15] = f2bf(sc0[r]);
      pw[(quad*4 + r)*ST_P + 16 + l15] = f2bf(sc1[r]);
    }

    // ---- rescale O by alpha ----
    #pragma unroll
    for (int nb = 0; nb < 4; nb++){
      #pragma unroll
      for (int r = 0; r < 4; r++) O[nb][r] *= al[r];
    }

    // ---- P A-frag from LDS + PV MFMAs ----
    bf16x4 plo = *(const bf16x4*)&pw[l15*ST_P + quad*8];
    bf16x4 phi = *(const bf16x4*)&pw[l15*ST_P + quad*8 + 4];
    bf16x8 pa;
    pa[0]=plo[0]; pa[1]=plo[1]; pa[2]=plo[2]; pa[3]=plo[3];
    pa[4]=phi[0]; pa[5]=phi[1]; pa[6]=phi[2]; pa[7]=phi[3];

    #pragma unroll
    for (int nb = 0; nb < 4; nb++){
      bf16x8 bv = *(const bf16x8*)&vlds[(nb*16 + l15)*32 + quad*8];
      O[nb] = __builtin_amdgcn_mfma_f32_16x16x32_bf16(pa, bv, O[nb], 0,0,0);
    }
  }

  // ---- epilogue: O / l, write ctx [B,S,H] fp32 ----
  float inv[4];
  #pragma unroll
  for (int r = 0; r < 4; r++) inv[r] = 1.0f / lr[r];
  #pragma unroll
  for (int nb = 0; nb < 4; nb++){
    #pragma unroll
    for (int r = 0; r < 4; r++){
      out[((size_t)b*SS + q0 + quad*4 + r)*HH + h*HDD + nb*16 + l15] = O[nb][r]*inv[r];
    }
  }
}

extern "C" void kernel_launch(void* const* d_in, const int* in_sizes, int n_in,
                              void* d_out, int out_size, void* d_ws, size_t ws_size,
                              hipStream_t stream){
  const float* hs   = (const float*)d_in[0];
  const float* mask = (const float*)d_in[1];
  const float* Wq   = (const float*)d_in[2];
  const float* bq   = (const float*)d_in[3];
  const float* Wk   = (const float*)d_in[4];
  const float* bk   = (const float*)d_in[5];
  const float* Wv   = (const float*)d_in[6];
  const float* bv   = (const float*)d_in[7];
  const float* qe   = (const float*)d_in[8];
  const float* ke   = (const float*)d_in[9];
  const float* ve   = (const float*)d_in[10];
  const int*   idx  = (const int*)d_in[11];
  unsigned short* ws16 = (unsigned short*)d_ws;
  float* out = (float*)d_out;

  convert_kernel<<<4096, 256, 0, stream>>>(hs, Wq, Wk, Wv, ws16);

  dim3 g2(M_TOT/64, HH/64, 3);
  qkv_gemm<<<g2, 256, 0, stream>>>(ws16, ws16, bq, bk, bv, qe, ke, ve, idx);

  attn_mfma<<<BB*NHH*SS/64, 256, 0, stream>>>(ws16, mask, out);
}

// Round 3
// 524.525 us; speedup vs baseline: 58.5495x; 1.5828x over previous
//
#include <hip/hip_runtime.h>
#include <stdint.h>

#define BB 4
#define SS 2048
#define HH 1024
#define NHH 16
#define HDD 64
#define M_TOT (BB*SS)          // 8192

// workspace layout (ushort/bf16 element offsets)
#define XB_OFF 0                              // hidden bf16 [8192][1024]
#define WT_OFF (M_TOT*HH)                     // Wq^T,Wk^T,Wv^T bf16 [3][N=1024][K=1024]
#define Q_OFF  (WT_OFF + 3*HH*HH)             // Q  [B][NH][S][HD]
#define K_OFF  (Q_OFF + BB*NHH*SS*HDD)        // K  [B][NH][S][HD]
#define VT_OFF (K_OFF + BB*NHH*SS*HDD)        // Vt [B][NH][HD][S]  (transposed)

typedef short bf16x8 __attribute__((ext_vector_type(8)));
typedef short bf16x4 __attribute__((ext_vector_type(4)));
typedef float f32x4  __attribute__((ext_vector_type(4)));

__device__ inline unsigned short f2bf(float f){
  unsigned u = __float_as_uint(f);
  u += 0x7fffu + ((u >> 16) & 1u);   // RNE
  return (unsigned short)(u >> 16);
}
__device__ inline float bf2f(unsigned short h){
  return __uint_as_float(((unsigned)h) << 16);
}

// async global->LDS, 16B per lane; LDS dest = wave-uniform base + lane*16
__device__ __forceinline__ void ld_g2l_16(const unsigned short* g, unsigned short* l){
  __builtin_amdgcn_global_load_lds(
      (const __attribute__((address_space(1))) void*)g,
      (__attribute__((address_space(3))) void*)l, 16, 0, 0);
}

// ---------------- kernel 1a: X fp32 -> bf16 (vectorized) ----------------
__global__ void convert_x(const float* __restrict__ hs, unsigned short* __restrict__ xb){
  const int i = blockIdx.x*blockDim.x + threadIdx.x;   // one float4 per thread
  float4 v = ((const float4*)hs)[i];
  ushort4 o;
  o.x = f2bf(v.x); o.y = f2bf(v.y); o.z = f2bf(v.z); o.w = f2bf(v.w);
  ((ushort4*)xb)[i] = o;
}

// ---------------- kernel 1b: W [K][N] fp32 -> WT [N][K] bf16, tiled transpose ----------------
__global__ void convert_wt(const float* __restrict__ wq, const float* __restrict__ wk,
                           const float* __restrict__ wv, unsigned short* __restrict__ wt){
  __shared__ unsigned short t[64][65];
  const int z = blockIdx.z;
  const float* W = (z==0) ? wq : ((z==1) ? wk : wv);
  unsigned short* WT = wt + z*HH*HH;
  const int kb = blockIdx.x*64, nb = blockIdx.y*64;
  const int tid = threadIdx.x;
  #pragma unroll
  for (int i = 0; i < 16; i++){
    const int idx = i*256 + tid;
    const int r = idx >> 6, c = idx & 63;
    t[r][c] = f2bf(W[(kb + r)*HH + nb + c]);    // coalesced read along n
  }
  __syncthreads();
  #pragma unroll
  for (int i = 0; i < 16; i++){
    const int idx = i*256 + tid;
    const int n = idx >> 6, k = idx & 63;
    WT[(nb + n)*HH + kb + k] = t[k][n];         // coalesced write along k
  }
}

// ---------------- kernel 2: QKV projection GEMM, m97 structure ----------------
// 128x128 block tile, BK=32, 4 waves 2x2 each 64x64, global_load_lds staging.
// grid (M/128, N/128, 3) = (64, 8, 3); block 256.
__global__ __launch_bounds__(256) void qkv_gemm(
    const unsigned short* __restrict__ ws16, unsigned short* __restrict__ wsq,
    const float* __restrict__ bq, const float* __restrict__ bk, const float* __restrict__ bv,
    const float* __restrict__ qe, const float* __restrict__ ke, const float* __restrict__ ve,
    const int* __restrict__ idxp){
  __shared__ unsigned short al[128*32];   // A tile [128 m][32 k] row-major
  __shared__ unsigned short bl[128*32];   // B tile [128 n][32 k] row-major (from WT)

  const unsigned short* Xb = ws16 + XB_OFF;
  const int z = blockIdx.z;
  const unsigned short* Wt = ws16 + WT_OFF + z*HH*HH;
  const float* bias = (z==0) ? bq : ((z==1) ? bk : bv);
  const float* emb  = (z==0) ? qe : ((z==1) ? ke : ve);

  const int tid  = threadIdx.x;
  const int wv   = tid >> 6;
  const int ln   = tid & 63;
  const int quad = ln >> 4;
  const int l15  = ln & 15;
  const int m0 = blockIdx.x * 128;
  const int n0 = blockIdx.y * 128;
  const int wm = wv & 1, wn = wv >> 1;

  // staging geometry: wave wv covers rows [wv*32, wv*32+32), 2 issues of 16 rows
  const int sr0 = wv*32 + (ln >> 2);
  const int sr1 = sr0 + 16;
  const int sk  = (ln & 3)*8;
  const unsigned short* ga0 = &Xb[(size_t)(m0 + sr0)*HH + sk];
  const unsigned short* ga1 = &Xb[(size_t)(m0 + sr1)*HH + sk];
  const unsigned short* gb0 = &Wt[(size_t)(n0 + sr0)*HH + sk];
  const unsigned short* gb1 = &Wt[(size_t)(n0 + sr1)*HH + sk];
  unsigned short* alb0 = &al[wv*1024];
  unsigned short* alb1 = &al[wv*1024 + 512];
  unsigned short* blb0 = &bl[wv*1024];
  unsigned short* blb1 = &bl[wv*1024 + 512];

  f32x4 acc[4][4] = {};

  for (int k0 = 0; k0 < HH; k0 += 32){
    __syncthreads();                       // previous tile fully consumed
    ld_g2l_16(ga0 + k0, alb0);
    ld_g2l_16(ga1 + k0, alb1);
    ld_g2l_16(gb0 + k0, blb0);
    ld_g2l_16(gb1 + k0, blb1);
    __syncthreads();                       // drains vmcnt (loads landed)

    bf16x8 af[4], bf[4];
    #pragma unroll
    for (int i = 0; i < 4; i++){
      af[i] = *(const bf16x8*)&al[(wm*64 + i*16 + l15)*32 + quad*8];
      bf[i] = *(const bf16x8*)&bl[(wn*64 + i*16 + l15)*32 + quad*8];
    }
    #pragma unroll
    for (int mi = 0; mi < 4; mi++)
      #pragma unroll
      for (int ni = 0; ni < 4; ni++)
        acc[mi][ni] = __builtin_amdgcn_mfma_f32_16x16x32_bf16(af[mi], bf[ni], acc[mi][ni], 0, 0, 0);
  }

  // epilogue: bias + task emb, cast, scatter into Q / K / VT layouts
  const int index = idxp[0];
  #pragma unroll
  for (int ni = 0; ni < 4; ni++){
    const int n = n0 + wn*64 + ni*16 + l15;
    const float biasv = bias[n] + emb[index*HH + n];
    const int h = n >> 6, d = n & 63;
    #pragma unroll
    for (int mi = 0; mi < 4; mi++){
      #pragma unroll
      for (int r = 0; r < 4; r++){
        const int g  = m0 + wm*64 + mi*16 + quad*4 + r;   // C/D: row=quad*4+reg, col=l15
        const int b_ = g >> 11;
        const int s_ = g & (SS - 1);
        const int bh = b_*NHH + h;
        const unsigned short val = f2bf(acc[mi][ni][r] + biasv);
        if (z == 2)      wsq[VT_OFF + (size_t)(bh*HDD + d)*SS + s_] = val;
        else if (z == 0) wsq[Q_OFF  + (size_t)(bh*SS + s_)*HDD + d] = val;
        else             wsq[K_OFF  + (size_t)(bh*SS + s_)*HDD + d] = val;
      }
    }
  }
}

// ---------------- kernel 3: MFMA flash attention (unchanged from R1) ----------------
#define ST_K 72
#define ST_P 36
__global__ __launch_bounds__(256) void attn_mfma(
    const unsigned short* __restrict__ ws16,
    const float* __restrict__ mask, float* __restrict__ out){
  __shared__ unsigned short klds[32*ST_K];
  __shared__ unsigned short vlds[64*32];
  __shared__ unsigned short plds[4][16*ST_P];
  __shared__ float mlds[SS];

  const int tid  = threadIdx.x;
  const int wave = tid >> 6;
  const int lane = tid & 63;
  const int quad = lane >> 4;
  const int l15  = lane & 15;
  const int qb   = blockIdx.x & 31;
  const int bh   = blockIdx.x >> 5;
  const int b    = bh >> 4, h = bh & 15;
  const int q0   = qb*64 + wave*16;

  {
    const float4* mp = (const float4*)(mask + b*SS);
    float4 a = mp[tid*2 + 0], c = mp[tid*2 + 1];
    *(float4*)&mlds[tid*8 + 0] = a;
    *(float4*)&mlds[tid*8 + 4] = c;
  }

  const unsigned short* Qg = ws16 + Q_OFF  + (size_t)bh*SS*HDD;
  const unsigned short* Kg = ws16 + K_OFF  + (size_t)bh*SS*HDD;
  const unsigned short* Vg = ws16 + VT_OFF + (size_t)bh*HDD*SS;

  const bf16x8 aq0 = *(const bf16x8*)(Qg + (q0 + l15)*HDD + quad*8);
  const bf16x8 aq1 = *(const bf16x8*)(Qg + (q0 + l15)*HDD + 32 + quad*8);

  f32x4 O[4] = { {0,0,0,0}, {0,0,0,0}, {0,0,0,0}, {0,0,0,0} };
  float mr[4] = {-1e30f,-1e30f,-1e30f,-1e30f};
  float lr[4] = {0.f,0.f,0.f,0.f};

  const int krow = tid >> 3, kcol = (tid & 7)*8;
  const int vrow = tid >> 2, vcol = (tid & 3)*8;
  const float LOG2E = 1.4426950408889634f;

  for (int t = 0; t < 64; t++){
    __syncthreads();
    *(bf16x8*)&klds[krow*ST_K + kcol] = *(const bf16x8*)&Kg[(t*32 + krow)*HDD + kcol];
    *(bf16x8*)&vlds[vrow*32  + vcol] = *(const bf16x8*)&Vg[vrow*SS + t*32 + vcol];
    __syncthreads();

    f32x4 sc0 = {0,0,0,0}, sc1 = {0,0,0,0};
    {
      bf16x8 b00 = *(const bf16x8*)&klds[(l15     )*ST_K      + quad*8];
      bf16x8 b01 = *(const bf16x8*)&klds[(l15     )*ST_K + 32 + quad*8];
      bf16x8 b10 = *(const bf16x8*)&klds[(16 + l15)*ST_K      + quad*8];
      bf16x8 b11 = *(const bf16x8*)&klds[(16 + l15)*ST_K + 32 + quad*8];
      sc0 = __builtin_amdgcn_mfma_f32_16x16x32_bf16(aq0, b00, sc0, 0,0,0);
      sc0 = __builtin_amdgcn_mfma_f32_16x16x32_bf16(aq1, b01, sc0, 0,0,0);
      sc1 = __builtin_amdgcn_mfma_f32_16x16x32_bf16(aq0, b10, sc1, 0,0,0);
      sc1 = __builtin_amdgcn_mfma_f32_16x16x32_bf16(aq1, b11, sc1, 0,0,0);
    }

    const float msk0 = mlds[t*32 + l15];
    const float msk1 = mlds[t*32 + 16 + l15];
    #pragma unroll
    for (int r = 0; r < 4; r++){
      sc0[r] = sc0[r]*0.125f + msk0;
      sc1[r] = sc1[r]*0.125f + msk1;
    }

    float mx[4];
    #pragma unroll
    for (int r = 0; r < 4; r++) mx[r] = fmaxf(sc0[r], sc1[r]);
    #pragma unroll
    for (int sh = 1; sh < 16; sh <<= 1){
      #pragma unroll
      for (int r = 0; r < 4; r++) mx[r] = fmaxf(mx[r], __shfl_xor(mx[r], sh));
    }
    float al_[4], su[4];
    #pragma unroll
    for (int r = 0; r < 4; r++){
      const float nm = fmaxf(mr[r], mx[r]);
      al_[r] = exp2f((mr[r] - nm)*LOG2E);
      mr[r] = nm;
      sc0[r] = exp2f((sc0[r] - nm)*LOG2E);
      sc1[r] = exp2f((sc1[r] - nm)*LOG2E);
      su[r] = sc0[r] + sc1[r];
    }
    #pragma unroll
    for (int sh = 1; sh < 16; sh <<= 1){
      #pragma unroll
      for (int r = 0; r < 4; r++) su[r] += __shfl_xor(su[r], sh);
    }
    #pragma unroll
    for (int r = 0; r < 4; r++) lr[r] = lr[r]*al_[r] + su[r];

    unsigned short* pw = &plds[wave][0];
    #pragma unroll
    for (int r = 0; r < 4; r++){
      pw[(quad*4 + r)*ST_P      + l15] = f2bf(sc0[r]);
      pw[(quad*4 + r)*ST_P + 16 + l15] = f2bf(sc1[r]);
    }

    #pragma unroll
    for (int nb = 0; nb < 4; nb++){
      #pragma unroll
      for (int r = 0; r < 4; r++) O[nb][r] *= al_[r];
    }

    bf16x4 plo = *(const bf16x4*)&pw[l15*ST_P + quad*8];
    bf16x4 phi = *(const bf16x4*)&pw[l15*ST_P + quad*8 + 4];
    bf16x8 pa;
    pa[0]=plo[0]; pa[1]=plo[1]; pa[2]=plo[2]; pa[3]=plo[3];
    pa[4]=phi[0]; pa[5]=phi[1]; pa[6]=phi[2]; pa[7]=phi[3];

    #pragma unroll
    for (int nb = 0; nb < 4; nb++){
      bf16x8 bvf = *(const bf16x8*)&vlds[(nb*16 + l15)*32 + quad*8];
      O[nb] = __builtin_amdgcn_mfma_f32_16x16x32_bf16(pa, bvf, O[nb], 0,0,0);
    }
  }

  float inv[4];
  #pragma unroll
  for (int r = 0; r < 4; r++) inv[r] = 1.0f / lr[r];
  #pragma unroll
  for (int nb = 0; nb < 4; nb++){
    #pragma unroll
    for (int r = 0; r < 4; r++){
      out[((size_t)b*SS + q0 + quad*4 + r)*HH + h*HDD + nb*16 + l15] = O[nb][r]*inv[r];
    }
  }
}

extern "C" void kernel_launch(void* const* d_in, const int* in_sizes, int n_in,
                              void* d_out, int out_size, void* d_ws, size_t ws_size,
                              hipStream_t stream){
  const float* hs   = (const float*)d_in[0];
  const float* mask = (const float*)d_in[1];
  const float* Wq   = (const float*)d_in[2];
  const float* bq   = (const float*)d_in[3];
  const float* Wk   = (const float*)d_in[4];
  const float* bk   = (const float*)d_in[5];
  const float* Wv   = (const float*)d_in[6];
  const float* bv   = (const float*)d_in[7];
  const float* qe   = (const float*)d_in[8];
  const float* ke   = (const float*)d_in[9];
  const float* ve   = (const float*)d_in[10];
  const int*   idx  = (const int*)d_in[11];
  unsigned short* ws16 = (unsigned short*)d_ws;
  float* out = (float*)d_out;

  convert_x<<<M_TOT*HH/4/256, 256, 0, stream>>>(hs, ws16 + XB_OFF);
  dim3 gt(HH/64, HH/64, 3);
  convert_wt<<<gt, 256, 0, stream>>>(Wq, Wk, Wv, ws16 + WT_OFF);

  dim3 g2(M_TOT/128, HH/128, 3);
  qkv_gemm<<<g2, 256, 0, stream>>>(ws16, ws16, bq, bk, bv, qe, ke, ve, idx);

  attn_mfma<<<BB*NHH*SS/64, 256, 0, stream>>>(ws16, mask, out);
}

// Round 4
// 373.510 us; speedup vs baseline: 82.2219x; 1.4043x over previous
//
#include <hip/hip_runtime.h>
#include <hip/hip_bf16.h>
#include <stdint.h>

#define BB 4
#define SS 2048
#define HH 1024
#define NHH 16
#define HDD 64
#define M_TOT (BB*SS)          // 8192

// workspace layout (ushort/bf16 element offsets)
#define XB_OFF 0                              // hidden bf16 [8192][1024]
#define WT_OFF (M_TOT*HH)                     // Wq^T,Wk^T,Wv^T bf16 [3][N=1024][K=1024]
#define Q_OFF  (WT_OFF + 3*HH*HH)             // Q  [B][NH][S][HD]
#define K_OFF  (Q_OFF + BB*NHH*SS*HDD)        // K  [B][NH][S][HD]
#define VT_OFF (K_OFF + BB*NHH*SS*HDD)        // Vt [B][NH][HD][S]  (transposed)

typedef short bf16x8 __attribute__((ext_vector_type(8)));
typedef short bf16x4 __attribute__((ext_vector_type(4)));
typedef float f32x4  __attribute__((ext_vector_type(4)));

__device__ inline unsigned short f2bf(float f){
  unsigned u = __float_as_uint(f);
  u += 0x7fffu + ((u >> 16) & 1u);   // RNE
  return (unsigned short)(u >> 16);
}
__device__ inline unsigned pk2bf(float lo, float hi){
  float2 t; t.x = lo; t.y = hi;
  __hip_bfloat162 h = __float22bfloat162_rn(t);   // v_cvt_pk_bf16_f32 where available
  return *(unsigned*)&h;
}

// async global->LDS, 16B per lane; LDS dest = wave-uniform base + lane*16
__device__ __forceinline__ void ld_g2l_16(const unsigned short* g, unsigned short* l){
  __builtin_amdgcn_global_load_lds(
      (const __attribute__((address_space(1))) void*)g,
      (__attribute__((address_space(3))) void*)l, 16, 0, 0);
}

// ---------------- kernel 1a: X fp32 -> bf16 (vectorized) ----------------
__global__ void convert_x(const float* __restrict__ hs, unsigned short* __restrict__ xb){
  const int i = blockIdx.x*blockDim.x + threadIdx.x;
  float4 v = ((const float4*)hs)[i];
  ushort4 o;
  o.x = f2bf(v.x); o.y = f2bf(v.y); o.z = f2bf(v.z); o.w = f2bf(v.w);
  ((ushort4*)xb)[i] = o;
}

// ---------------- kernel 1b: W [K][N] fp32 -> WT [N][K] bf16 ----------------
__global__ void convert_wt(const float* __restrict__ wq, const float* __restrict__ wk,
                           const float* __restrict__ wv, unsigned short* __restrict__ wt){
  __shared__ unsigned short t[64][65];
  const int z = blockIdx.z;
  const float* W = (z==0) ? wq : ((z==1) ? wk : wv);
  unsigned short* WT = wt + z*HH*HH;
  const int kb = blockIdx.x*64, nb = blockIdx.y*64;
  const int tid = threadIdx.x;
  #pragma unroll
  for (int i = 0; i < 16; i++){
    const int idx = i*256 + tid;
    const int r = idx >> 6, c = idx & 63;
    t[r][c] = f2bf(W[(kb + r)*HH + nb + c]);
  }
  __syncthreads();
  #pragma unroll
  for (int i = 0; i < 16; i++){
    const int idx = i*256 + tid;
    const int n = idx >> 6, k = idx & 63;
    WT[(nb + n)*HH + kb + k] = t[k][n];
  }
}

// ---------------- kernel 2: QKV projection GEMM (m97 structure, unchanged) ----------------
__global__ __launch_bounds__(256) void qkv_gemm(
    const unsigned short* __restrict__ ws16, unsigned short* __restrict__ wsq,
    const float* __restrict__ bq, const float* __restrict__ bk, const float* __restrict__ bv,
    const float* __restrict__ qe, const float* __restrict__ ke, const float* __restrict__ ve,
    const int* __restrict__ idxp){
  __shared__ unsigned short al[128*32];
  __shared__ unsigned short bl[128*32];

  const unsigned short* Xb = ws16 + XB_OFF;
  const int z = blockIdx.z;
  const unsigned short* Wt = ws16 + WT_OFF + z*HH*HH;
  const float* bias = (z==0) ? bq : ((z==1) ? bk : bv);
  const float* emb  = (z==0) ? qe : ((z==1) ? ke : ve);

  const int tid  = threadIdx.x;
  const int wv   = tid >> 6;
  const int ln   = tid & 63;
  const int quad = ln >> 4;
  const int l15  = ln & 15;
  const int m0 = blockIdx.x * 128;
  const int n0 = blockIdx.y * 128;
  const int wm = wv & 1, wn = wv >> 1;

  const int sr0 = wv*32 + (ln >> 2);
  const int sr1 = sr0 + 16;
  const int sk  = (ln & 3)*8;
  const unsigned short* ga0 = &Xb[(size_t)(m0 + sr0)*HH + sk];
  const unsigned short* ga1 = &Xb[(size_t)(m0 + sr1)*HH + sk];
  const unsigned short* gb0 = &Wt[(size_t)(n0 + sr0)*HH + sk];
  const unsigned short* gb1 = &Wt[(size_t)(n0 + sr1)*HH + sk];
  unsigned short* alb0 = &al[wv*1024];
  unsigned short* alb1 = &al[wv*1024 + 512];
  unsigned short* blb0 = &bl[wv*1024];
  unsigned short* blb1 = &bl[wv*1024 + 512];

  f32x4 acc[4][4] = {};

  for (int k0 = 0; k0 < HH; k0 += 32){
    __syncthreads();
    ld_g2l_16(ga0 + k0, alb0);
    ld_g2l_16(ga1 + k0, alb1);
    ld_g2l_16(gb0 + k0, blb0);
    ld_g2l_16(gb1 + k0, blb1);
    __syncthreads();

    bf16x8 af[4], bf[4];
    #pragma unroll
    for (int i = 0; i < 4; i++){
      af[i] = *(const bf16x8*)&al[(wm*64 + i*16 + l15)*32 + quad*8];
      bf[i] = *(const bf16x8*)&bl[(wn*64 + i*16 + l15)*32 + quad*8];
    }
    #pragma unroll
    for (int mi = 0; mi < 4; mi++)
      #pragma unroll
      for (int ni = 0; ni < 4; ni++)
        acc[mi][ni] = __builtin_amdgcn_mfma_f32_16x16x32_bf16(af[mi], bf[ni], acc[mi][ni], 0, 0, 0);
  }

  const int index = idxp[0];
  #pragma unroll
  for (int ni = 0; ni < 4; ni++){
    const int n = n0 + wn*64 + ni*16 + l15;
    const float biasv = bias[n] + emb[index*HH + n];
    const int h = n >> 6, d = n & 63;
    #pragma unroll
    for (int mi = 0; mi < 4; mi++){
      #pragma unroll
      for (int r = 0; r < 4; r++){
        const int g  = m0 + wm*64 + mi*16 + quad*4 + r;
        const int b_ = g >> 11;
        const int s_ = g & (SS - 1);
        const int bh = b_*NHH + h;
        const unsigned short val = f2bf(acc[mi][ni][r] + biasv);
        if (z == 2)      wsq[VT_OFF + (size_t)(bh*HDD + d)*SS + s_] = val;
        else if (z == 0) wsq[Q_OFF  + (size_t)(bh*SS + s_)*HDD + d] = val;
        else             wsq[K_OFF  + (size_t)(bh*SS + s_)*HDD + d] = val;
      }
    }
  }
}

// ---------------- kernel 3: MFMA flash attention, transposed (S^T/O^T) ----------------
// Fixed-max softmax (scores are O(10): exp2 args bounded, no overflow in fp32).
// block 256 = 4 waves x 16 q rows; kt-tile = 64; grid = (B*NH)*(S/64) = 2048.
#define ST_K 72   // klds/vlds row stride (shorts): 144B, 16B-aligned, <=2-way/phase
#define ST_P 72   // plds row stride (shorts)
__global__ __launch_bounds__(256) void attn_mfma(
    const unsigned short* __restrict__ ws16,
    const float* __restrict__ mask, float* __restrict__ out){
  __shared__ unsigned short klds[64*ST_K];     // K tile  [64 kt][64 d]
  __shared__ unsigned short vlds[64*ST_K];     // V^T tile[64 d][64 kt]
  __shared__ unsigned short plds[4][16*ST_P];  // per-wave P^T as [16 q][64 kt]
  __shared__ float mlds[SS];                   // mask row * log2(e)

  const int tid  = threadIdx.x;
  const int wave = tid >> 6;
  const int lane = tid & 63;
  const int quad = lane >> 4;
  const int l15  = lane & 15;
  const int qb   = blockIdx.x & 31;
  const int bh   = blockIdx.x >> 5;
  const int b    = bh >> 4, h = bh & 15;
  const int q0   = qb*64 + wave*16;
  const float LOG2E = 1.4426950408889634f;
  const float SC = 0.125f * LOG2E;             // 1/sqrt(64) * log2(e)

  // stage mask row, pre-scaled by log2(e)
  {
    const float4* mp = (const float4*)(mask + b*SS);
    float4 a = mp[tid*2 + 0], c = mp[tid*2 + 1];
    a.x*=LOG2E; a.y*=LOG2E; a.z*=LOG2E; a.w*=LOG2E;
    c.x*=LOG2E; c.y*=LOG2E; c.z*=LOG2E; c.w*=LOG2E;
    *(float4*)&mlds[tid*8 + 0] = a;
    *(float4*)&mlds[tid*8 + 4] = c;
  }

  const unsigned short* Qg = ws16 + Q_OFF  + (size_t)bh*SS*HDD;
  const unsigned short* Kg = ws16 + K_OFF  + (size_t)bh*SS*HDD;
  const unsigned short* Vg = ws16 + VT_OFF + (size_t)bh*HDD*SS;

  // Q fragment (resident): element (q=l15, d=quad*8+j) serves as B-operand Q^T[d][q]
  const bf16x8 aq0 = *(const bf16x8*)(Qg + (q0 + l15)*HDD + quad*8);
  const bf16x8 aq1 = *(const bf16x8*)(Qg + (q0 + l15)*HDD + 32 + quad*8);

  f32x4 O[4] = { {0,0,0,0}, {0,0,0,0}, {0,0,0,0}, {0,0,0,0} };  // O^T[d=nb*16+quad*4+r][q=l15]
  float lacc = 0.f;                                              // partial l for q=l15

  // staging geometry: 256 threads, 16B each, 2 issues per array
  const int srow = tid >> 3;            // 0..31
  const int scol = (tid & 7)*8;
  unsigned short* pw = &plds[wave][0];

  for (int t = 0; t < 32; t++){
    __syncthreads();
    // K tile [kt][d]
    *(bf16x8*)&klds[(srow     )*ST_K + scol] = *(const bf16x8*)&Kg[(size_t)(t*64 + srow     )*HDD + scol];
    *(bf16x8*)&klds[(srow + 32)*ST_K + scol] = *(const bf16x8*)&Kg[(size_t)(t*64 + srow + 32)*HDD + scol];
    // V^T tile [d][kt]
    *(bf16x8*)&vlds[(srow     )*ST_K + scol] = *(const bf16x8*)&Vg[(size_t)(srow     )*SS + t*64 + scol];
    *(bf16x8*)&vlds[(srow + 32)*ST_K + scol] = *(const bf16x8*)&Vg[(size_t)(srow + 32)*SS + t*64 + scol];
    __syncthreads();

    // ---- S^T = K · Q^T : 4 frags, each [16 kt][16 q] ----
    #pragma unroll
    for (int fi = 0; fi < 4; fi++){
      bf16x8 k0 = *(const bf16x8*)&klds[(fi*16 + l15)*ST_K      + quad*8];
      bf16x8 k1 = *(const bf16x8*)&klds[(fi*16 + l15)*ST_K + 32 + quad*8];
      f32x4 st = {0,0,0,0};
      st = __builtin_amdgcn_mfma_f32_16x16x32_bf16(k0, aq0, st, 0,0,0);
      st = __builtin_amdgcn_mfma_f32_16x16x32_bf16(k1, aq1, st, 0,0,0);

      // mask values for kt = t*64 + fi*16 + quad*4 + r (broadcast across l15 lanes)
      const f32x4 mv = *(const f32x4*)&mlds[t*64 + fi*16 + quad*4];

      // p = exp2(s*0.125*log2e + m*log2e); accumulate l per lane (q = l15)
      f32x4 p;
      #pragma unroll
      for (int r = 0; r < 4; r++) p[r] = exp2f(fmaf(st[r], SC, mv[r]));
      lacc += (p[0] + p[1]) + (p[2] + p[3]);

      // P^T store: row q=l15, cols kt = fi*16 + quad*4 .. +3 (packed b64, conflict-free)
      uint2 w; w.x = pk2bf(p[0], p[1]); w.y = pk2bf(p[2], p[3]);
      *(uint2*)&pw[l15*ST_P + fi*16 + quad*4] = w;
    }

    // ---- O^T += V^T · P^T (intra-wave LDS round-trip, no barrier) ----
    #pragma unroll
    for (int c = 0; c < 2; c++){
      bf16x8 bp = *(const bf16x8*)&pw[l15*ST_P + c*32 + quad*8];
      #pragma unroll
      for (int nb = 0; nb < 4; nb++){
        bf16x8 av = *(const bf16x8*)&vlds[(nb*16 + l15)*ST_K + c*32 + quad*8];
        O[nb] = __builtin_amdgcn_mfma_f32_16x16x32_bf16(av, bp, O[nb], 0,0,0);
      }
    }
  }

  // ---- l reduction across quads (lanes l15+16k all hold q=l15 partials) ----
  float lq = lacc;
  lq += __shfl_xor(lq, 16);
  lq += __shfl_xor(lq, 32);
  const float inv = 1.0f / lq;

  // ---- write ctx [B,S,H] fp32: row q = q0+l15, cols d = nb*16+quad*4+r ----
  float* op = out + ((size_t)b*SS + q0 + l15)*HH + h*HDD;
  #pragma unroll
  for (int nb = 0; nb < 4; nb++){
    float4 o;
    o.x = O[nb][0]*inv; o.y = O[nb][1]*inv; o.z = O[nb][2]*inv; o.w = O[nb][3]*inv;
    *(float4*)&op[nb*16 + quad*4] = o;
  }
}

extern "C" void kernel_launch(void* const* d_in, const int* in_sizes, int n_in,
                              void* d_out, int out_size, void* d_ws, size_t ws_size,
                              hipStream_t stream){
  const float* hs   = (const float*)d_in[0];
  const float* mask = (const float*)d_in[1];
  const float* Wq   = (const float*)d_in[2];
  const float* bq   = (const float*)d_in[3];
  const float* Wk   = (const float*)d_in[4];
  const float* bk   = (const float*)d_in[5];
  const float* Wv   = (const float*)d_in[6];
  const float* bv   = (const float*)d_in[7];
  const float* qe   = (const float*)d_in[8];
  const float* ke   = (const float*)d_in[9];
  const float* ve   = (const float*)d_in[10];
  const int*   idx  = (const int*)d_in[11];
  unsigned short* ws16 = (unsigned short*)d_ws;
  float* out = (float*)d_out;

  convert_x<<<M_TOT*HH/4/256, 256, 0, stream>>>(hs, ws16 + XB_OFF);
  dim3 gt(HH/64, HH/64, 3);
  convert_wt<<<gt, 256, 0, stream>>>(Wq, Wk, Wv, ws16 + WT_OFF);

  dim3 g2(M_TOT/128, HH/128, 3);
  qkv_gemm<<<g2, 256, 0, stream>>>(ws16, ws16, bq, bk, bv, qe, ke, ve, idx);

  attn_mfma<<<BB*NHH*SS/64, 256, 0, stream>>>(ws16, mask, out);
}

// Round 5
// 345.131 us; speedup vs baseline: 88.9826x; 1.0822x over previous
//
#include <hip/hip_runtime.h>
#include <hip/hip_bf16.h>
#include <stdint.h>

#define BB 4
#define SS 2048
#define HH 1024
#define NHH 16
#define HDD 64
#define M_TOT (BB*SS)          // 8192

// workspace layout (ushort/bf16 element offsets)
#define XB_OFF 0                              // hidden bf16 [8192][1024]
#define WT_OFF (M_TOT*HH)                     // Wq^T,Wk^T,Wv^T bf16 [3][N=1024][K=1024]
#define Q_OFF  (WT_OFF + 3*HH*HH)             // Q  [B][NH][S][HD]
#define K_OFF  (Q_OFF + BB*NHH*SS*HDD)        // K  [B][NH][S][HD]
#define VT_OFF (K_OFF + BB*NHH*SS*HDD)        // Vt [B][NH][HD][S]  (transposed)

typedef short bf16x8 __attribute__((ext_vector_type(8)));
typedef float f32x4  __attribute__((ext_vector_type(4)));

__device__ inline unsigned short f2bf(float f){
  unsigned u = __float_as_uint(f);
  u += 0x7fffu + ((u >> 16) & 1u);   // RNE
  return (unsigned short)(u >> 16);
}
__device__ inline unsigned pk2bf(float lo, float hi){
  float2 t; t.x = lo; t.y = hi;
  __hip_bfloat162 h = __float22bfloat162_rn(t);
  return *(unsigned*)&h;
}

// async global->LDS, 16B per lane
__device__ __forceinline__ void ld_g2l_16(const unsigned short* g, unsigned short* l){
  __builtin_amdgcn_global_load_lds(
      (const __attribute__((address_space(1))) void*)g,
      (__attribute__((address_space(3))) void*)l, 16, 0, 0);
}

// ---------------- kernel 1a: X fp32 -> bf16 ----------------
__global__ void convert_x(const float* __restrict__ hs, unsigned short* __restrict__ xb){
  const int i = blockIdx.x*blockDim.x + threadIdx.x;
  float4 v = ((const float4*)hs)[i];
  ushort4 o;
  o.x = f2bf(v.x); o.y = f2bf(v.y); o.z = f2bf(v.z); o.w = f2bf(v.w);
  ((ushort4*)xb)[i] = o;
}

// ---------------- kernel 1b: W [K][N] fp32 -> WT [N][K] bf16 ----------------
__global__ void convert_wt(const float* __restrict__ wq, const float* __restrict__ wk,
                           const float* __restrict__ wv, unsigned short* __restrict__ wt){
  __shared__ unsigned short t[64][65];
  const int z = blockIdx.z;
  const float* W = (z==0) ? wq : ((z==1) ? wk : wv);
  unsigned short* WT = wt + z*HH*HH;
  const int kb = blockIdx.x*64, nb = blockIdx.y*64;
  const int tid = threadIdx.x;
  #pragma unroll
  for (int i = 0; i < 16; i++){
    const int idx = i*256 + tid;
    const int r = idx >> 6, c = idx & 63;
    t[r][c] = f2bf(W[(kb + r)*HH + nb + c]);
  }
  __syncthreads();
  #pragma unroll
  for (int i = 0; i < 16; i++){
    const int idx = i*256 + tid;
    const int n = idx >> 6, k = idx & 63;
    WT[(nb + n)*HH + kb + k] = t[k][n];
  }
}

// ---------------- kernel 2: QKV projection GEMM (m97 structure, unchanged) ----------------
__global__ __launch_bounds__(256) void qkv_gemm(
    const unsigned short* __restrict__ ws16, unsigned short* __restrict__ wsq,
    const float* __restrict__ bq, const float* __restrict__ bk, const float* __restrict__ bv,
    const float* __restrict__ qe, const float* __restrict__ ke, const float* __restrict__ ve,
    const int* __restrict__ idxp){
  __shared__ unsigned short al[128*32];
  __shared__ unsigned short bl[128*32];

  const unsigned short* Xb = ws16 + XB_OFF;
  const int z = blockIdx.z;
  const unsigned short* Wt = ws16 + WT_OFF + z*HH*HH;
  const float* bias = (z==0) ? bq : ((z==1) ? bk : bv);
  const float* emb  = (z==0) ? qe : ((z==1) ? ke : ve);

  const int tid  = threadIdx.x;
  const int wv   = tid >> 6;
  const int ln   = tid & 63;
  const int quad = ln >> 4;
  const int l15  = ln & 15;
  const int m0 = blockIdx.x * 128;
  const int n0 = blockIdx.y * 128;
  const int wm = wv & 1, wn = wv >> 1;

  const int sr0 = wv*32 + (ln >> 2);
  const int sr1 = sr0 + 16;
  const int sk  = (ln & 3)*8;
  const unsigned short* ga0 = &Xb[(size_t)(m0 + sr0)*HH + sk];
  const unsigned short* ga1 = &Xb[(size_t)(m0 + sr1)*HH + sk];
  const unsigned short* gb0 = &Wt[(size_t)(n0 + sr0)*HH + sk];
  const unsigned short* gb1 = &Wt[(size_t)(n0 + sr1)*HH + sk];
  unsigned short* alb0 = &al[wv*1024];
  unsigned short* alb1 = &al[wv*1024 + 512];
  unsigned short* blb0 = &bl[wv*1024];
  unsigned short* blb1 = &bl[wv*1024 + 512];

  f32x4 acc[4][4] = {};

  for (int k0 = 0; k0 < HH; k0 += 32){
    __syncthreads();
    ld_g2l_16(ga0 + k0, alb0);
    ld_g2l_16(ga1 + k0, alb1);
    ld_g2l_16(gb0 + k0, blb0);
    ld_g2l_16(gb1 + k0, blb1);
    __syncthreads();

    bf16x8 af[4], bf[4];
    #pragma unroll
    for (int i = 0; i < 4; i++){
      af[i] = *(const bf16x8*)&al[(wm*64 + i*16 + l15)*32 + quad*8];
      bf[i] = *(const bf16x8*)&bl[(wn*64 + i*16 + l15)*32 + quad*8];
    }
    #pragma unroll
    for (int mi = 0; mi < 4; mi++)
      #pragma unroll
      for (int ni = 0; ni < 4; ni++)
        acc[mi][ni] = __builtin_amdgcn_mfma_f32_16x16x32_bf16(af[mi], bf[ni], acc[mi][ni], 0, 0, 0);
  }

  const int index = idxp[0];
  #pragma unroll
  for (int ni = 0; ni < 4; ni++){
    const int n = n0 + wn*64 + ni*16 + l15;
    const float biasv = bias[n] + emb[index*HH + n];
    const int h = n >> 6, d = n & 63;
    #pragma unroll
    for (int mi = 0; mi < 4; mi++){
      #pragma unroll
      for (int r = 0; r < 4; r++){
        const int g  = m0 + wm*64 + mi*16 + quad*4 + r;
        const int b_ = g >> 11;
        const int s_ = g & (SS - 1);
        const int bh = b_*NHH + h;
        const unsigned short val = f2bf(acc[mi][ni][r] + biasv);
        if (z == 2)      wsq[VT_OFF + (size_t)(bh*HDD + d)*SS + s_] = val;
        else if (z == 0) wsq[Q_OFF  + (size_t)(bh*SS + s_)*HDD + d] = val;
        else             wsq[K_OFF  + (size_t)(bh*SS + s_)*HDD + d] = val;
      }
    }
  }
}

// ---------------- kernel 3: flash attention, kt split across waves ----------------
// Block = 64 q rows (shared), wave w owns kt in [w*512,(w+1)*512), 16 chunks of 32.
// Fixed-max softmax -> per-wave partial l and O merge by plain addition at the end.
// K/V^T fragments load directly global->VGPR (MFMA A-layout, coalesced).
// LDS: per-wave P^T round-trip only + O/l merge buffers + mask. No main-loop barriers.
#define ST_P 40   // plds row stride (shorts): 80B, 16B-aligned, uniform banks
#define ST_O 68   // obuf row stride (dwords): 272B, 16B-aligned, uniform banks for b128
__global__ __launch_bounds__(256) void attn_mfma(
    const unsigned short* __restrict__ ws16,
    const float* __restrict__ mask, float* __restrict__ out){
  __shared__ unsigned short plds[4][64*ST_P];  // per-wave P^T [64 q][32 kt]
  __shared__ float obuf[64][ST_O];             // merged O^T as [q][d]
  __shared__ float lpart[4][64];               // per-wave l partials
  __shared__ float mlds[SS];                   // mask row * log2(e)

  const int tid  = threadIdx.x;
  const int wave = tid >> 6;
  const int lane = tid & 63;
  const int quad = lane >> 4;
  const int l15  = lane & 15;
  const int qb   = blockIdx.x & 31;
  const int bh   = blockIdx.x >> 5;
  const int b    = bh >> 4, h = bh & 15;
  const int q0   = qb*64;
  const float LOG2E = 1.4426950408889634f;
  const float SC = 0.125f * LOG2E;             // 1/sqrt(64) * log2(e)

  // stage mask row, pre-scaled by log2(e)
  {
    const float4* mp = (const float4*)(mask + b*SS);
    float4 a = mp[tid*2 + 0], c = mp[tid*2 + 1];
    a.x*=LOG2E; a.y*=LOG2E; a.z*=LOG2E; a.w*=LOG2E;
    c.x*=LOG2E; c.y*=LOG2E; c.z*=LOG2E; c.w*=LOG2E;
    *(float4*)&mlds[tid*8 + 0] = a;
    *(float4*)&mlds[tid*8 + 4] = c;
  }
  __syncthreads();

  const unsigned short* Qg = ws16 + Q_OFF  + (size_t)bh*SS*HDD;
  const unsigned short* Kg = ws16 + K_OFF  + (size_t)bh*SS*HDD;
  const unsigned short* Vg = ws16 + VT_OFF + (size_t)bh*HDD*SS;

  // Q fragments for all 64 q rows (B-operand: n=q=qg*16+l15, k=d=quad*8+j), resident
  bf16x8 aq[4][2];
  #pragma unroll
  for (int qg = 0; qg < 4; qg++){
    aq[qg][0] = *(const bf16x8*)(Qg + (size_t)(q0 + qg*16 + l15)*HDD + quad*8);
    aq[qg][1] = *(const bf16x8*)(Qg + (size_t)(q0 + qg*16 + l15)*HDD + 32 + quad*8);
  }

  f32x4 O[4][4] = {};          // O^T partial: [dg][qg], elem (d=dg*16+quad*4+r, q=qg*16+l15)
  float lacc[4] = {0.f,0.f,0.f,0.f};
  unsigned short* pw = &plds[wave][0];

  #pragma unroll 2
  for (int ch = 0; ch < 16; ch++){
    const int ktb = wave*512 + ch*32;

    // K fragments: A-operand (m=kt=fi*16+l15, k=d), direct from global
    bf16x8 ka[2][2];
    #pragma unroll
    for (int fi = 0; fi < 2; fi++){
      ka[fi][0] = *(const bf16x8*)&Kg[(size_t)(ktb + fi*16 + l15)*HDD + quad*8];
      ka[fi][1] = *(const bf16x8*)&Kg[(size_t)(ktb + fi*16 + l15)*HDD + 32 + quad*8];
    }
    // V^T fragments: A-operand (m=d=dg*16+l15, k=kt=quad*8+j), direct from global
    bf16x8 va[4];
    #pragma unroll
    for (int dg = 0; dg < 4; dg++)
      va[dg] = *(const bf16x8*)&Vg[(size_t)(dg*16 + l15)*SS + ktb + quad*8];

    // ---- S^T = K·Q^T -> p = exp2(s*SC + mask) -> P^T to LDS ----
    #pragma unroll
    for (int fi = 0; fi < 2; fi++){
      const f32x4 mv = *(const f32x4*)&mlds[ktb + fi*16 + quad*4];
      #pragma unroll
      for (int qg = 0; qg < 4; qg++){
        f32x4 st = {0,0,0,0};
        st = __builtin_amdgcn_mfma_f32_16x16x32_bf16(ka[fi][0], aq[qg][0], st, 0,0,0);
        st = __builtin_amdgcn_mfma_f32_16x16x32_bf16(ka[fi][1], aq[qg][1], st, 0,0,0);
        f32x4 p;
        #pragma unroll
        for (int r = 0; r < 4; r++) p[r] = exp2f(fmaf(st[r], SC, mv[r]));
        lacc[qg] += (p[0] + p[1]) + (p[2] + p[3]);
        uint2 w; w.x = pk2bf(p[0], p[1]); w.y = pk2bf(p[2], p[3]);
        *(uint2*)&pw[(qg*16 + l15)*ST_P + fi*16 + quad*4] = w;
      }
    }

    // ---- O^T += V^T · P^T (intra-wave LDS round-trip, wave-ordered, no barrier) ----
    #pragma unroll
    for (int qg = 0; qg < 4; qg++){
      bf16x8 bp = *(const bf16x8*)&pw[(qg*16 + l15)*ST_P + quad*8];
      #pragma unroll
      for (int dg = 0; dg < 4; dg++)
        O[dg][qg] = __builtin_amdgcn_mfma_f32_16x16x32_bf16(va[dg], bp, O[dg][qg], 0,0,0);
    }
  }

  // ---- l partials: reduce across quads (shfl), store per wave ----
  #pragma unroll
  for (int qg = 0; qg < 4; qg++){
    float lq = lacc[qg];
    lq += __shfl_xor(lq, 16);
    lq += __shfl_xor(lq, 32);
    if (quad == 0) lpart[wave][qg*16 + l15] = lq;
  }

  // ---- phased O merge into obuf (float4, conflict-free) ----
  #pragma unroll
  for (int w = 0; w < 4; w++){
    if (wave == w){
      #pragma unroll
      for (int qg = 0; qg < 4; qg++){
        #pragma unroll
        for (int dg = 0; dg < 4; dg++){
          float* dst = &obuf[qg*16 + l15][dg*16 + quad*4];
          f32x4 v = O[dg][qg];
          if (w != 0){ f32x4 o = *(f32x4*)dst; v[0]+=o[0]; v[1]+=o[1]; v[2]+=o[2]; v[3]+=o[3]; }
          *(f32x4*)dst = v;
        }
      }
    }
    __syncthreads();
  }

  // ---- epilogue: scale by 1/l, write ctx [B,S,H] fp32 ----
  const int q  = tid >> 2;
  const int c4 = tid & 3;
  const float ls = lpart[0][q] + lpart[1][q] + lpart[2][q] + lpart[3][q];
  const float inv = 1.0f / ls;
  float* op = out + ((size_t)b*SS + q0 + q)*HH + h*HDD + c4*16;
  #pragma unroll
  for (int i = 0; i < 4; i++){
    f32x4 v = *(f32x4*)&obuf[q][c4*16 + i*4];
    float4 o; o.x = v[0]*inv; o.y = v[1]*inv; o.z = v[2]*inv; o.w = v[3]*inv;
    *(float4*)&op[i*4] = o;
  }
}

extern "C" void kernel_launch(void* const* d_in, const int* in_sizes, int n_in,
                              void* d_out, int out_size, void* d_ws, size_t ws_size,
                              hipStream_t stream){
  const float* hs   = (const float*)d_in[0];
  const float* mask = (const float*)d_in[1];
  const float* Wq   = (const float*)d_in[2];
  const float* bq   = (const float*)d_in[3];
  const float* Wk   = (const float*)d_in[4];
  const float* bk   = (const float*)d_in[5];
  const float* Wv   = (const float*)d_in[6];
  const float* bv   = (const float*)d_in[7];
  const float* qe   = (const float*)d_in[8];
  const float* ke   = (const float*)d_in[9];
  const float* ve   = (const float*)d_in[10];
  const int*   idx  = (const int*)d_in[11];
  unsigned short* ws16 = (unsigned short*)d_ws;
  float* out = (float*)d_out;

  convert_x<<<M_TOT*HH/4/256, 256, 0, stream>>>(hs, ws16 + XB_OFF);
  dim3 gt(HH/64, HH/64, 3);
  convert_wt<<<gt, 256, 0, stream>>>(Wq, Wk, Wv, ws16 + WT_OFF);

  dim3 g2(M_TOT/128, HH/128, 3);
  qkv_gemm<<<g2, 256, 0, stream>>>(ws16, ws16, bq, bk, bv, qe, ke, ve, idx);

  attn_mfma<<<BB*NHH*SS/64, 256, 0, stream>>>(ws16, mask, out);
}

// Round 6
// 343.593 us; speedup vs baseline: 89.3812x; 1.0045x over previous
//
#include <hip/hip_runtime.h>
#include <hip/hip_bf16.h>
#include <stdint.h>

#define BB 4
#define SS 2048
#define HH 1024
#define NHH 16
#define HDD 64
#define M_TOT (BB*SS)          // 8192

// workspace layout (ushort/bf16 element offsets)
#define XB_OFF 0                              // hidden bf16 [8192][1024]
#define WT_OFF (M_TOT*HH)                     // Wq^T,Wk^T,Wv^T bf16 [3][N=1024][K=1024]
#define Q_OFF  (WT_OFF + 3*HH*HH)             // Q  [B][NH][S][HD]  (pre-scaled by 0.125*log2e!)
#define K_OFF  (Q_OFF + BB*NHH*SS*HDD)        // K  [B][NH][S][HD]
#define VT_OFF (K_OFF + BB*NHH*SS*HDD)        // Vt [B][NH][HD][S]  (transposed)

typedef short bf16x8 __attribute__((ext_vector_type(8)));
typedef float f32x4  __attribute__((ext_vector_type(4)));

__device__ inline unsigned short f2bf(float f){
  unsigned u = __float_as_uint(f);
  u += 0x7fffu + ((u >> 16) & 1u);   // RNE
  return (unsigned short)(u >> 16);
}
__device__ inline unsigned pk2bf(float lo, float hi){
  float2 t; t.x = lo; t.y = hi;
  __hip_bfloat162 h = __float22bfloat162_rn(t);
  return *(unsigned*)&h;
}

// async global->LDS, 16B per lane
__device__ __forceinline__ void ld_g2l_16(const unsigned short* g, unsigned short* l){
  __builtin_amdgcn_global_load_lds(
      (const __attribute__((address_space(1))) void*)g,
      (__attribute__((address_space(3))) void*)l, 16, 0, 0);
}

// ---------------- kernel 1a: X fp32 -> bf16 ----------------
__global__ void convert_x(const float* __restrict__ hs, unsigned short* __restrict__ xb){
  const int i = blockIdx.x*blockDim.x + threadIdx.x;
  float4 v = ((const float4*)hs)[i];
  ushort4 o;
  o.x = f2bf(v.x); o.y = f2bf(v.y); o.z = f2bf(v.z); o.w = f2bf(v.w);
  ((ushort4*)xb)[i] = o;
}

// ---------------- kernel 1b: W [K][N] fp32 -> WT [N][K] bf16 ----------------
__global__ void convert_wt(const float* __restrict__ wq, const float* __restrict__ wk,
                           const float* __restrict__ wv, unsigned short* __restrict__ wt){
  __shared__ unsigned short t[64][65];
  const int z = blockIdx.z;
  const float* W = (z==0) ? wq : ((z==1) ? wk : wv);
  unsigned short* WT = wt + z*HH*HH;
  const int kb = blockIdx.x*64, nb = blockIdx.y*64;
  const int tid = threadIdx.x;
  #pragma unroll
  for (int i = 0; i < 16; i++){
    const int idx = i*256 + tid;
    const int r = idx >> 6, c = idx & 63;
    t[r][c] = f2bf(W[(kb + r)*HH + nb + c]);
  }
  __syncthreads();
  #pragma unroll
  for (int i = 0; i < 16; i++){
    const int idx = i*256 + tid;
    const int n = idx >> 6, k = idx & 63;
    WT[(nb + n)*HH + kb + k] = t[k][n];
  }
}

// ---------------- kernel 2: QKV projection GEMM (m97 structure) ----------------
// z==0 (Q) output is pre-scaled by 0.125*log2e so attention needs no per-score fma.
__global__ __launch_bounds__(256) void qkv_gemm(
    const unsigned short* __restrict__ ws16, unsigned short* __restrict__ wsq,
    const float* __restrict__ bq, const float* __restrict__ bk, const float* __restrict__ bv,
    const float* __restrict__ qe, const float* __restrict__ ke, const float* __restrict__ ve,
    const int* __restrict__ idxp){
  __shared__ unsigned short al[128*32];
  __shared__ unsigned short bl[128*32];

  const unsigned short* Xb = ws16 + XB_OFF;
  const int z = blockIdx.z;
  const unsigned short* Wt = ws16 + WT_OFF + z*HH*HH;
  const float* bias = (z==0) ? bq : ((z==1) ? bk : bv);
  const float* emb  = (z==0) ? qe : ((z==1) ? ke : ve);

  const int tid  = threadIdx.x;
  const int wv   = tid >> 6;
  const int ln   = tid & 63;
  const int quad = ln >> 4;
  const int l15  = ln & 15;
  const int m0 = blockIdx.x * 128;
  const int n0 = blockIdx.y * 128;
  const int wm = wv & 1, wn = wv >> 1;

  const int sr0 = wv*32 + (ln >> 2);
  const int sr1 = sr0 + 16;
  const int sk  = (ln & 3)*8;
  const unsigned short* ga0 = &Xb[(size_t)(m0 + sr0)*HH + sk];
  const unsigned short* ga1 = &Xb[(size_t)(m0 + sr1)*HH + sk];
  const unsigned short* gb0 = &Wt[(size_t)(n0 + sr0)*HH + sk];
  const unsigned short* gb1 = &Wt[(size_t)(n0 + sr1)*HH + sk];
  unsigned short* alb0 = &al[wv*1024];
  unsigned short* alb1 = &al[wv*1024 + 512];
  unsigned short* blb0 = &bl[wv*1024];
  unsigned short* blb1 = &bl[wv*1024 + 512];

  f32x4 acc[4][4] = {};

  for (int k0 = 0; k0 < HH; k0 += 32){
    __syncthreads();
    ld_g2l_16(ga0 + k0, alb0);
    ld_g2l_16(ga1 + k0, alb1);
    ld_g2l_16(gb0 + k0, blb0);
    ld_g2l_16(gb1 + k0, blb1);
    __syncthreads();

    bf16x8 af[4], bf[4];
    #pragma unroll
    for (int i = 0; i < 4; i++){
      af[i] = *(const bf16x8*)&al[(wm*64 + i*16 + l15)*32 + quad*8];
      bf[i] = *(const bf16x8*)&bl[(wn*64 + i*16 + l15)*32 + quad*8];
    }
    #pragma unroll
    for (int mi = 0; mi < 4; mi++)
      #pragma unroll
      for (int ni = 0; ni < 4; ni++)
        acc[mi][ni] = __builtin_amdgcn_mfma_f32_16x16x32_bf16(af[mi], bf[ni], acc[mi][ni], 0, 0, 0);
  }

  const int index = idxp[0];
  const float oscale = (z==0) ? 0.18033688011112042f : 1.0f;  // 0.125*log2(e) for Q
  #pragma unroll
  for (int ni = 0; ni < 4; ni++){
    const int n = n0 + wn*64 + ni*16 + l15;
    const float biasv = bias[n] + emb[index*HH + n];
    const int h = n >> 6, d = n & 63;
    #pragma unroll
    for (int mi = 0; mi < 4; mi++){
      #pragma unroll
      for (int r = 0; r < 4; r++){
        const int g  = m0 + wm*64 + mi*16 + quad*4 + r;
        const int b_ = g >> 11;
        const int s_ = g & (SS - 1);
        const int bh = b_*NHH + h;
        const unsigned short val = f2bf((acc[mi][ni][r] + biasv) * oscale);
        if (z == 2)      wsq[VT_OFF + (size_t)(bh*HDD + d)*SS + s_] = val;
        else if (z == 0) wsq[Q_OFF  + (size_t)(bh*SS + s_)*HDD + d] = val;
        else             wsq[K_OFF  + (size_t)(bh*SS + s_)*HDD + d] = val;
      }
    }
  }
}

// ---------------- kernel 3: flash attention, kt split across waves ----------------
// Block = 64 q rows (shared), wave w owns kt in [w*512,(w+1)*512), 16 chunks of 32.
// Fixed-max softmax; Q pre-scaled by 0.125*log2e; mask (x log2e) enters as the
// S-MFMA accumulator init -> p = exp2(st) with zero per-score VALU fma.
// LDS: plds (main loop) unioned with obuf/lpart (merge phase) -> 28.7 KB total.
#define ST_P 40   // plds row stride (shorts): 80B, 16B-aligned
#define ST_O 68   // obuf row stride (dwords): 272B, 16B-aligned
__global__ __launch_bounds__(256) void attn_mfma(
    const unsigned short* __restrict__ ws16,
    const float* __restrict__ mask, float* __restrict__ out){
  __shared__ __align__(16) unsigned char shraw[4*64*ST_P*2];  // 20480 B, dual-purpose
  __shared__ float mlds[SS];                                  // mask row * log2(e)

  unsigned short* plds = (unsigned short*)shraw;      // [4][64*ST_P] during main loop
  float (*obuf)[ST_O]  = (float(*)[ST_O])shraw;       // [64][ST_O] during merge (17408 B)
  float* lpart         = (float*)(shraw + 17408);     // [4][64] during merge (1024 B)

  const int tid  = threadIdx.x;
  const int wave = tid >> 6;
  const int lane = tid & 63;
  const int quad = lane >> 4;
  const int l15  = lane & 15;
  const int qb   = blockIdx.x & 31;
  const int bh   = blockIdx.x >> 5;
  const int b    = bh >> 4, h = bh & 15;
  const int q0   = qb*64;
  const float LOG2E = 1.4426950408889634f;

  // stage mask row, pre-scaled by log2(e)
  {
    const float4* mp = (const float4*)(mask + b*SS);
    float4 a = mp[tid*2 + 0], c = mp[tid*2 + 1];
    a.x*=LOG2E; a.y*=LOG2E; a.z*=LOG2E; a.w*=LOG2E;
    c.x*=LOG2E; c.y*=LOG2E; c.z*=LOG2E; c.w*=LOG2E;
    *(float4*)&mlds[tid*8 + 0] = a;
    *(float4*)&mlds[tid*8 + 4] = c;
  }
  __syncthreads();

  const unsigned short* Qg = ws16 + Q_OFF  + (size_t)bh*SS*HDD;
  const unsigned short* Kg = ws16 + K_OFF  + (size_t)bh*SS*HDD;
  const unsigned short* Vg = ws16 + VT_OFF + (size_t)bh*HDD*SS;

  // Q fragments for all 64 q rows (B-operand: n=q=qg*16+l15, k=d=quad*8+j), resident
  bf16x8 aq[4][2];
  #pragma unroll
  for (int qg = 0; qg < 4; qg++){
    aq[qg][0] = *(const bf16x8*)(Qg + (size_t)(q0 + qg*16 + l15)*HDD + quad*8);
    aq[qg][1] = *(const bf16x8*)(Qg + (size_t)(q0 + qg*16 + l15)*HDD + 32 + quad*8);
  }

  f32x4 O[4][4] = {};          // O^T partial: [dg][qg], elem (d=dg*16+quad*4+r, q=qg*16+l15)
  float lacc[4] = {0.f,0.f,0.f,0.f};
  unsigned short* pw = &plds[wave*64*ST_P];

  #pragma unroll 2
  for (int ch = 0; ch < 16; ch++){
    const int ktb = wave*512 + ch*32;

    // K fragments: A-operand (m=kt=fi*16+l15, k=d), direct from global
    bf16x8 ka[2][2];
    #pragma unroll
    for (int fi = 0; fi < 2; fi++){
      ka[fi][0] = *(const bf16x8*)&Kg[(size_t)(ktb + fi*16 + l15)*HDD + quad*8];
      ka[fi][1] = *(const bf16x8*)&Kg[(size_t)(ktb + fi*16 + l15)*HDD + 32 + quad*8];
    }
    // V^T fragments: A-operand (m=d=dg*16+l15, k=kt=quad*8+j), direct from global
    bf16x8 va[4];
    #pragma unroll
    for (int dg = 0; dg < 4; dg++)
      va[dg] = *(const bf16x8*)&Vg[(size_t)(dg*16 + l15)*SS + ktb + quad*8];

    // ---- S^T = K·Q^T with C init = mask -> p = exp2(st) -> P^T to LDS ----
    #pragma unroll
    for (int fi = 0; fi < 2; fi++){
      const f32x4 mv = *(const f32x4*)&mlds[ktb + fi*16 + quad*4];
      #pragma unroll
      for (int qg = 0; qg < 4; qg++){
        f32x4 st = mv;   // accumulator pre-loaded with log2e-scaled mask
        st = __builtin_amdgcn_mfma_f32_16x16x32_bf16(ka[fi][0], aq[qg][0], st, 0,0,0);
        st = __builtin_amdgcn_mfma_f32_16x16x32_bf16(ka[fi][1], aq[qg][1], st, 0,0,0);
        f32x4 p;
        #pragma unroll
        for (int r = 0; r < 4; r++) p[r] = exp2f(st[r]);
        lacc[qg] += (p[0] + p[1]) + (p[2] + p[3]);
        uint2 w; w.x = pk2bf(p[0], p[1]); w.y = pk2bf(p[2], p[3]);
        *(uint2*)&pw[(qg*16 + l15)*ST_P + fi*16 + quad*4] = w;
      }
    }

    // ---- O^T += V^T · P^T (intra-wave LDS round-trip, wave-ordered, no barrier) ----
    #pragma unroll
    for (int qg = 0; qg < 4; qg++){
      bf16x8 bp = *(const bf16x8*)&pw[(qg*16 + l15)*ST_P + quad*8];
      #pragma unroll
      for (int dg = 0; dg < 4; dg++)
        O[dg][qg] = __builtin_amdgcn_mfma_f32_16x16x32_bf16(va[dg], bp, O[dg][qg], 0,0,0);
    }
  }

  // ---- all waves done with plds; switch region to obuf/lpart ----
  __syncthreads();

  // l partials: reduce across quads (shfl), store per wave
  #pragma unroll
  for (int qg = 0; qg < 4; qg++){
    float lq = lacc[qg];
    lq += __shfl_xor(lq, 16);
    lq += __shfl_xor(lq, 32);
    if (quad == 0) lpart[wave*64 + qg*16 + l15] = lq;
  }

  // phased O merge into obuf (float4, conflict-free)
  #pragma unroll
  for (int w = 0; w < 4; w++){
    if (wave == w){
      #pragma unroll
      for (int qg = 0; qg < 4; qg++){
        #pragma unroll
        for (int dg = 0; dg < 4; dg++){
          float* dst = &obuf[qg*16 + l15][dg*16 + quad*4];
          f32x4 v = O[dg][qg];
          if (w != 0){ f32x4 o = *(f32x4*)dst; v[0]+=o[0]; v[1]+=o[1]; v[2]+=o[2]; v[3]+=o[3]; }
          *(f32x4*)dst = v;
        }
      }
    }
    __syncthreads();
  }

  // epilogue: scale by 1/l, write ctx [B,S,H] fp32
  const int q  = tid >> 2;
  const int c4 = tid & 3;
  const float ls = lpart[0*64 + q] + lpart[1*64 + q] + lpart[2*64 + q] + lpart[3*64 + q];
  const float inv = 1.0f / ls;
  float* op = out + ((size_t)b*SS + q0 + q)*HH + h*HDD + c4*16;
  #pragma unroll
  for (int i = 0; i < 4; i++){
    f32x4 v = *(f32x4*)&obuf[q][c4*16 + i*4];
    float4 o; o.x = v[0]*inv; o.y = v[1]*inv; o.z = v[2]*inv; o.w = v[3]*inv;
    *(float4*)&op[i*4] = o;
  }
}

extern "C" void kernel_launch(void* const* d_in, const int* in_sizes, int n_in,
                              void* d_out, int out_size, void* d_ws, size_t ws_size,
                              hipStream_t stream){
  const float* hs   = (const float*)d_in[0];
  const float* mask = (const float*)d_in[1];
  const float* Wq   = (const float*)d_in[2];
  const float* bq   = (const float*)d_in[3];
  const float* Wk   = (const float*)d_in[4];
  const float* bk   = (const float*)d_in[5];
  const float* Wv   = (const float*)d_in[6];
  const float* bv   = (const float*)d_in[7];
  const float* qe   = (const float*)d_in[8];
  const float* ke   = (const float*)d_in[9];
  const float* ve   = (const float*)d_in[10];
  const int*   idx  = (const int*)d_in[11];
  unsigned short* ws16 = (unsigned short*)d_ws;
  float* out = (float*)d_out;

  convert_x<<<M_TOT*HH/4/256, 256, 0, stream>>>(hs, ws16 + XB_OFF);
  dim3 gt(HH/64, HH/64, 3);
  convert_wt<<<gt, 256, 0, stream>>>(Wq, Wk, Wv, ws16 + WT_OFF);

  dim3 g2(M_TOT/128, HH/128, 3);
  qkv_gemm<<<g2, 256, 0, stream>>>(ws16, ws16, bq, bk, bv, qe, ke, ve, idx);

  attn_mfma<<<BB*NHH*SS/64, 256, 0, stream>>>(ws16, mask, out);
}